// Round 1
// baseline (93931.104 us; speedup 1.0000x reference)
//
#include <hip/hip_runtime.h>
#include <cstddef>
#include <cstdint>

#define DEVFN __device__ __forceinline__

DEVFN float sigmf(float x) { return 1.0f / (1.0f + __expf(-x)); }

template <int BM, int BN, int BK, int TM, int TN>
__launch_bounds__(256)
__global__ void gemm_nt(const float* __restrict__ A, int lda,
                        const float* __restrict__ W, int ldw,
                        float* __restrict__ C, int ldc,
                        const float* __restrict__ addA, int ldaA,
                        const float* __restrict__ bias,
                        const float* __restrict__ prelu,
                        const float* __restrict__ addB, int ldaB,
                        int N, int K, int accum)
{
    __shared__ float As[BM][BK + 1];
    __shared__ float Ws[BN][BK + 1];
    const int tid = threadIdx.x;
    const int m0 = blockIdx.y * BM;
    const int n0 = blockIdx.x * BN;
    const int tn = tid % (BN / TN);
    const int tm = tid / (BN / TN);

    float acc[TM][TN];
#pragma unroll
    for (int i = 0; i < TM; ++i)
#pragma unroll
        for (int j = 0; j < TN; ++j) acc[i][j] = 0.f;

    for (int k0 = 0; k0 < K; k0 += BK) {
#pragma unroll
        for (int i = tid; i < BM * BK; i += 256) {
            int r = i / BK, cc = i % BK;
            As[r][cc] = A[(size_t)(m0 + r) * lda + k0 + cc];
        }
#pragma unroll
        for (int i = tid; i < BN * BK; i += 256) {
            int r = i / BK, cc = i % BK;
            int n = n0 + r;
            Ws[r][cc] = (n < N) ? W[(size_t)n * ldw + k0 + cc] : 0.f;
        }
        __syncthreads();
#pragma unroll
        for (int kk = 0; kk < BK; ++kk) {
            float a[TM], b[TN];
#pragma unroll
            for (int i = 0; i < TM; ++i) a[i] = As[tm * TM + i][kk];
#pragma unroll
            for (int j = 0; j < TN; ++j) b[j] = Ws[tn * TN + j][kk];
#pragma unroll
            for (int i = 0; i < TM; ++i)
#pragma unroll
                for (int j = 0; j < TN; ++j) acc[i][j] = fmaf(a[i], b[j], acc[i][j]);
        }
        __syncthreads();
    }

    const float pw = prelu ? *prelu : 0.f;
#pragma unroll
    for (int i = 0; i < TM; ++i) {
        int m = m0 + tm * TM + i;
#pragma unroll
        for (int j = 0; j < TN; ++j) {
            int n = n0 + tn * TN + j;
            if (n < N) {
                float v = acc[i][j];
                if (bias) v += bias[n];
                if (prelu) v = (v >= 0.f) ? v : pw * v;
                if (addB) v += addB[(size_t)m * ldaB + n];
                if (addA) v += addA[(size_t)m * ldaA + n];
                size_t ci = (size_t)m * ldc + n;
                if (accum) C[ci] += v; else C[ci] = v;
            }
        }
    }
}

__launch_bounds__(256)
__global__ void lstm_gates(const float* __restrict__ g, float* __restrict__ h,
                           float* __restrict__ c, float* __restrict__ h_store)
{
    int idx = blockIdx.x * 256 + threadIdx.x;   // 0..65535
    int b = idx >> 10, j = idx & 1023;
    const float* gr = g + (size_t)b * 4096;
    float gi = gr[j], gf = gr[1024 + j], gg = gr[2048 + j], go = gr[3072 + j];
    float cv = c[idx];
    float cn = sigmf(gf) * cv + sigmf(gi) * tanhf(gg);
    float hn = sigmf(go) * tanhf(cn);
    c[idx] = cn;
    h[idx] = hn;
    if (h_store) h_store[idx] = hn;
}

__launch_bounds__(256)
__global__ void attention_step(const float* __restrict__ h,
                               const float* __restrict__ sample,
                               const float* __restrict__ W1,
                               const float* __restrict__ b1,
                               const float* __restrict__ E,
                               float* __restrict__ attA,
                               float* __restrict__ xdec)
{
    int b = blockIdx.x, tid = threadIdx.x;
    __shared__ float sm[2048];
    __shared__ float wsm[80];
    __shared__ float rbuf[128];

    for (int i = tid; i < 1024; i += 256) {
        sm[i] = h[b * 1024 + i];
        sm[1024 + i] = sample[b * 1024 + i];
    }
    __syncthreads();

    int wave = tid >> 6, lane = tid & 63;
    for (int s = wave; s < 80; s += 4) {
        float p = 0.f;
        const float* wr = W1 + (size_t)s * 2048;
        for (int k = lane; k < 2048; k += 64) p = fmaf(sm[k], wr[k], p);
        for (int off = 32; off; off >>= 1) p += __shfl_down(p, off, 64);
        if (lane == 0) wsm[s] = p + b1[s];
    }
    __syncthreads();

    float v = (tid < 80) ? wsm[tid] : -3.4e38f;
    if (tid < 128) rbuf[tid] = v;
    __syncthreads();
    for (int off = 64; off >= 1; off >>= 1) {
        if (tid < off) rbuf[tid] = fmaxf(rbuf[tid], rbuf[tid + off]);
        __syncthreads();
    }
    float mx = rbuf[0];
    __syncthreads();
    float e = (tid < 80) ? __expf(wsm[tid] - mx) : 0.f;
    if (tid < 128) rbuf[tid] = e;
    __syncthreads();
    for (int off = 64; off >= 1; off >>= 1) {
        if (tid < off) rbuf[tid] += rbuf[tid + off];
        __syncthreads();
    }
    float inv = 1.f / rbuf[0];
    __syncthreads();
    if (tid < 80) wsm[tid] = e * inv;
    __syncthreads();

    for (int hh = tid; hh < 1024; hh += 256) {
        float acc = 0.f;
        for (int s = 0; s < 80; ++s)
            acc = fmaf(wsm[s], E[((size_t)s * 64 + b) * 1024 + hh], acc);
        attA[b * 2048 + 1024 + hh] = acc;     // f
        float smp = sm[1024 + hh];
        attA[b * 2048 + hh] = smp;            // sample into attA[:,0:1024]
        xdec[b * 2048 + hh] = smp;            // sample into xdec[:,0:1024]
    }
}

__launch_bounds__(256)
__global__ void vec_add2(const float* __restrict__ a, const float* __restrict__ b,
                         float* __restrict__ o, int n)
{
    int i = blockIdx.x * 256 + threadIdx.x;
    if (i < n) o[i] = a[i] + b[i];
}

__launch_bounds__(256)
__global__ void fill0(float* __restrict__ p, int n)
{
    int i = blockIdx.x * 256 + threadIdx.x;
    if (i < n) p[i] = 0.f;
}

__launch_bounds__(256)
__global__ void sample0_fill(const float* __restrict__ emW, const float* __restrict__ emb,
                             float* __restrict__ samples)
{
    int idx = blockIdx.x * 256 + threadIdx.x; // 65536
    int d = idx & 1023;
    samples[idx] = emW[(size_t)d * 20000 + 19998] + emb[d];
}

extern "C" void kernel_launch(void* const* d_in, const int* in_sizes, int n_in,
                              void* d_out, int out_size, void* d_ws, size_t ws_size,
                              hipStream_t stream)
{
    (void)in_sizes; (void)n_in; (void)out_size; (void)ws_size;

    const float* input_data     = (const float*)d_in[0];
    const float* correct_answer = (const float*)d_in[1];
    const float* enc_W_ih = (const float*)d_in[2];
    const float* enc_W_hh = (const float*)d_in[3];
    const float* enc_b_ih = (const float*)d_in[4];
    const float* enc_b_hh = (const float*)d_in[5];
    const float* dec_W_ih = (const float*)d_in[6];
    const float* dec_W_hh = (const float*)d_in[7];
    const float* dec_b_ih = (const float*)d_in[8];
    const float* dec_b_hh = (const float*)d_in[9];
    const float* in_emb_W = (const float*)d_in[10];
    const float* in_emb_b = (const float*)d_in[11];
    const float* out_emb_W = (const float*)d_in[12];
    const float* out_emb_b = (const float*)d_in[13];
    const float* att_W1 = (const float*)d_in[14];
    const float* att_b1 = (const float*)d_in[15];
    const float* att_W2 = (const float*)d_in[16];
    const float* att_b2 = (const float*)d_in[17];
    const float* prelu_w = (const float*)d_in[18];

    float* out = (float*)d_out;
    char* ws = (char*)d_ws;

    // Xbig (80*64*4096 f32 = 84 MB) borrows d_out as scratch; its last read
    // (decoder warm-up) finishes before the final vocab GEMM overwrites d_out.
    float* Xbig = out;

    size_t off = 0;
    auto alloc = [&](size_t nfloats) { float* p = (float*)(ws + off); off += nfloats * 4; return p; };
    float* enc_seq     = alloc(80 * 64 * 1024);
    float* enc_pad_seq = alloc(80 * 64 * 1024);
    float* samples     = alloc(80 * 64 * 1024);
    float* h_all       = alloc(80 * 64 * 1024);
    float* gbuf        = alloc(64 * 4096);
    float* h_enc = alloc(64 * 1024);
    float* c_enc = alloc(64 * 1024);
    float* h_dec = alloc(64 * 1024);
    float* c_dec = alloc(64 * 1024);
    float* attA  = alloc(64 * 2048);
    float* xdec  = alloc(64 * 2048);
    float* benc_sum = alloc(4096);
    float* bdec_sum = alloc(4096);

    const float* NUL = nullptr;

    auto gemmA = [&](const float* A, int lda, const float* W, int ldw,
                     float* C, int ldc, const float* bias, int M, int N, int K) {
        dim3 g((N + 63) / 64, M / 64);
        hipLaunchKernelGGL((gemm_nt<64, 64, 16, 4, 4>), g, dim3(256), 0, stream,
                           A, lda, W, ldw, C, ldc, NUL, 0, bias, NUL, NUL, 0, N, K, 0);
    };
    auto gemmB = [&](const float* A, int lda, const float* W, int ldw,
                     float* C, int ldc, const float* addA, int ldaA,
                     const float* bias, const float* prelu,
                     const float* addB, int ldaB, int N, int K, int accum) {
        dim3 g(N / 16, 1);
        hipLaunchKernelGGL((gemm_nt<64, 16, 32, 4, 1>), g, dim3(256), 0, stream,
                           A, lda, W, ldw, C, ldc, addA, ldaA, bias, prelu, addB, ldaB, N, K, accum);
    };
    auto gates = [&](float* h, float* c, float* h_store) {
        hipLaunchKernelGGL(lstm_gates, dim3(256), dim3(256), 0, stream, gbuf, h, c, h_store);
    };
    auto zero = [&](float* p, int n) {
        hipLaunchKernelGGL(fill0, dim3((n + 255) / 256), dim3(256), 0, stream, p, n);
    };

    // setup
    hipLaunchKernelGGL(vec_add2, dim3(16), dim3(256), 0, stream, enc_b_ih, enc_b_hh, benc_sum, 4096);
    hipLaunchKernelGGL(vec_add2, dim3(16), dim3(256), 0, stream, dec_b_ih, dec_b_hh, bdec_sum, 4096);
    zero(h_enc, 65536); zero(c_enc, 65536);

    // encoder input projection
    gemmA(input_data, 4096, enc_W_ih, 4096, Xbig, 4096, benc_sum, 5120, 4096, 4096);

    // encoder recurrence
    for (int t = 0; t < 80; ++t) {
        gemmB(h_enc, 1024, enc_W_hh, 1024, gbuf, 4096,
              Xbig + (size_t)t * 64 * 4096, 4096, NUL, NUL, NUL, 0, 4096, 1024, 0);
        gates(h_enc, c_enc, enc_seq + (size_t)t * 64 * 1024);
    }

    // encoder over zero padding (continues encoder state)
    for (int t = 0; t < 80; ++t) {
        gemmB(h_enc, 1024, enc_W_hh, 1024, gbuf, 4096,
              NUL, 0, benc_sum, NUL, NUL, 0, 4096, 1024, 0);
        gates(h_enc, c_enc, enc_pad_seq + (size_t)t * 64 * 1024);
    }

    // decoder warm-up input projection (dec_in0 = [enc_seq | zeros] -> only first 1024 cols of dec_W_ih)
    gemmA(enc_seq, 1024, dec_W_ih, 2048, Xbig, 4096, bdec_sum, 5120, 4096, 1024);

    // decoder warm-up recurrence
    zero(h_dec, 65536); zero(c_dec, 65536);
    for (int t = 0; t < 80; ++t) {
        gemmB(h_dec, 1024, dec_W_hh, 1024, gbuf, 4096,
              Xbig + (size_t)t * 64 * 4096, 4096, NUL, NUL, NUL, 0, 4096, 1024, 0);
        gates(h_dec, c_dec, nullptr);
    }

    // teacher-forced samples
    hipLaunchKernelGGL(sample0_fill, dim3(256), dim3(256), 0, stream, in_emb_W, in_emb_b, samples);
    gemmA(correct_answer + (size_t)64 * 20000, 20000, in_emb_W, 20000,
          samples + (size_t)64 * 1024, 1024, in_emb_b, 5056, 1024, 20000);

    // attention decode loop
    for (int t = 0; t < 80; ++t) {
        const float* sample_t = samples + (size_t)t * 64 * 1024;
        const float* encpad_t = enc_pad_seq + (size_t)t * 64 * 1024;
        hipLaunchKernelGGL(attention_step, dim3(64), dim3(256), 0, stream,
                           h_dec, sample_t, att_W1, att_b1, enc_seq, attA, xdec);
        // context = prelu([sample|f] @ W2^T + b2) + enc_pad[t] -> xdec[:,1024:2048]
        gemmB(attA, 2048, att_W2, 2048, xdec + 1024, 2048,
              NUL, 0, att_b2, prelu_w, encpad_t, 1024, 1024, 2048, 0);
        // g = [sample|context] @ dec_W_ih^T + (b_ih+b_hh); g += h @ dec_W_hh^T
        gemmB(xdec, 2048, dec_W_ih, 2048, gbuf, 4096,
              NUL, 0, bdec_sum, NUL, NUL, 0, 4096, 2048, 0);
        gemmB(h_dec, 1024, dec_W_hh, 1024, gbuf, 4096,
              NUL, 0, NUL, NUL, NUL, 0, 4096, 1024, 1);
        gates(h_dec, c_dec, h_all + (size_t)t * 64 * 1024);
    }

    // final vocab projection directly into d_out
    gemmA(h_all, 1024, out_emb_W, 1024, out, 20000, out_emb_b, 5120, 20000, 1024);
}

// Round 2
// 40323.389 us; speedup vs baseline: 2.3294x; 2.3294x over previous
//
#include <hip/hip_runtime.h>
#include <cstddef>
#include <cstdint>

__device__ __forceinline__ float sigmf(float x) { return 1.0f / (1.0f + __expf(-x)); }

// ---------------------------------------------------------------------------
// Big fp32 GEMM: C[M,N] = A[M,K] @ W[N,K]^T + bias.  BM=BN=128, BK=16, 8x8/thr.
// M,N guarded (loads clamped, stores guarded). K must be a multiple of 16.
// ---------------------------------------------------------------------------
__launch_bounds__(256)
__global__ void gemm_big(const float* __restrict__ A, int lda,
                         const float* __restrict__ W, int ldw,
                         float* __restrict__ C, int ldc,
                         const float* __restrict__ bias,
                         int M, int N, int K)
{
    __shared__ float As[16][132];
    __shared__ float Ws[16][132];
    const int tid = threadIdx.x;
    const int m0 = blockIdx.y * 128;
    const int n0 = blockIdx.x * 128;
    const int tm = tid >> 4, tn = tid & 15;

    float acc[8][8];
#pragma unroll
    for (int i = 0; i < 8; ++i)
#pragma unroll
        for (int j = 0; j < 8; ++j) acc[i][j] = 0.f;

    for (int k0 = 0; k0 < K; k0 += 16) {
#pragma unroll
        for (int it = 0; it < 2; ++it) {
            int li = tid + it * 256;           // 0..511
            int m = li >> 2, k4 = li & 3;
            int row = m0 + m; if (row > M - 1) row = M - 1;
            float4 v = *(const float4*)(A + (size_t)row * lda + k0 + k4 * 4);
            As[k4 * 4 + 0][m] = v.x; As[k4 * 4 + 1][m] = v.y;
            As[k4 * 4 + 2][m] = v.z; As[k4 * 4 + 3][m] = v.w;
        }
#pragma unroll
        for (int it = 0; it < 2; ++it) {
            int li = tid + it * 256;
            int n = li >> 2, k4 = li & 3;
            int row = n0 + n; if (row > N - 1) row = N - 1;
            float4 v = *(const float4*)(W + (size_t)row * ldw + k0 + k4 * 4);
            Ws[k4 * 4 + 0][n] = v.x; Ws[k4 * 4 + 1][n] = v.y;
            Ws[k4 * 4 + 2][n] = v.z; Ws[k4 * 4 + 3][n] = v.w;
        }
        __syncthreads();
#pragma unroll
        for (int kk = 0; kk < 16; ++kk) {
            float4 a0 = *(const float4*)&As[kk][tm * 8];
            float4 a1 = *(const float4*)&As[kk][tm * 8 + 4];
            float4 b0 = *(const float4*)&Ws[kk][tn * 8];
            float4 b1 = *(const float4*)&Ws[kk][tn * 8 + 4];
            float a[8] = {a0.x, a0.y, a0.z, a0.w, a1.x, a1.y, a1.z, a1.w};
            float b[8] = {b0.x, b0.y, b0.z, b0.w, b1.x, b1.y, b1.z, b1.w};
#pragma unroll
            for (int i = 0; i < 8; ++i)
#pragma unroll
                for (int j = 0; j < 8; ++j) acc[i][j] = fmaf(a[i], b[j], acc[i][j]);
        }
        __syncthreads();
    }

#pragma unroll
    for (int i = 0; i < 8; ++i) {
        int m = m0 + tm * 8 + i;
        if (m < M) {
#pragma unroll
            for (int j = 0; j < 8; ++j) {
                int n = n0 + tn * 8 + j;
                if (n < N) C[(size_t)m * ldc + n] = acc[i][j] + bias[n];
            }
        }
    }
}

// ---------------------------------------------------------------------------
// Split-K skinny GEMM for recurrent steps: gpart[ks][64][N] partial of
// [A1|A2][64, K1+K2] @ [W1|W2][N, K1+K2]^T over K-chunk ks.
// Tile 64(batch) x 64(n), 4x4/thread, transposed LDS with float4 reads.
// KC (=(K1+K2)/gridDim.y) must be a multiple of 32; K1 a multiple of 4.
// ---------------------------------------------------------------------------
__launch_bounds__(256)
__global__ void step_gemm(const float* __restrict__ A1, int lda1, int K1,
                          const float* __restrict__ W1, int ldw1,
                          const float* __restrict__ A2, int lda2,
                          const float* __restrict__ W2, int ldw2,
                          float* __restrict__ gpart, int N, int KC)
{
    __shared__ float Ast[32][68];
    __shared__ float Wst[32][68];
    const int tid = threadIdx.x;
    const int n0 = blockIdx.x * 64;
    const int ks = blockIdx.y;
    const int kbase = ks * KC;
    const int tm = tid >> 4, tn = tid & 15;

    float acc[4][4];
#pragma unroll
    for (int i = 0; i < 4; ++i)
#pragma unroll
        for (int j = 0; j < 4; ++j) acc[i][j] = 0.f;

    for (int kt = 0; kt < KC; kt += 32) {
        const int k0 = kbase + kt;
#pragma unroll
        for (int it = 0; it < 2; ++it) {
            int li = tid + it * 256;           // 0..511
            int m = li >> 3, k4 = li & 7;
            int kg = k0 + k4 * 4;
            float4 v = (kg < K1)
                ? *(const float4*)(A1 + (size_t)m * lda1 + kg)
                : *(const float4*)(A2 + (size_t)m * lda2 + (kg - K1));
            Ast[k4 * 4 + 0][m] = v.x; Ast[k4 * 4 + 1][m] = v.y;
            Ast[k4 * 4 + 2][m] = v.z; Ast[k4 * 4 + 3][m] = v.w;
        }
#pragma unroll
        for (int it = 0; it < 2; ++it) {
            int li = tid + it * 256;
            int r = li >> 3, k4 = li & 7;
            int kg = k0 + k4 * 4;
            int n = n0 + r;
            float4 v = (kg < K1)
                ? *(const float4*)(W1 + (size_t)n * ldw1 + kg)
                : *(const float4*)(W2 + (size_t)n * ldw2 + (kg - K1));
            Wst[k4 * 4 + 0][r] = v.x; Wst[k4 * 4 + 1][r] = v.y;
            Wst[k4 * 4 + 2][r] = v.z; Wst[k4 * 4 + 3][r] = v.w;
        }
        __syncthreads();
#pragma unroll
        for (int kk = 0; kk < 32; ++kk) {
            float4 a4 = *(const float4*)&Ast[kk][tm * 4];
            float4 b4 = *(const float4*)&Wst[kk][tn * 4];
            float a[4] = {a4.x, a4.y, a4.z, a4.w};
            float b[4] = {b4.x, b4.y, b4.z, b4.w};
#pragma unroll
            for (int i = 0; i < 4; ++i)
#pragma unroll
                for (int j = 0; j < 4; ++j) acc[i][j] = fmaf(a[i], b[j], acc[i][j]);
        }
        __syncthreads();
    }

#pragma unroll
    for (int i = 0; i < 4; ++i) {
        int m = tm * 4 + i;
        float4 v = make_float4(acc[i][0], acc[i][1], acc[i][2], acc[i][3]);
        *(float4*)(gpart + ((size_t)(ks * 64 + m)) * N + n0 + tn * 4) = v;
    }
}

// ---------------------------------------------------------------------------
// Combine 4 split-K partials (+Xbig or +bias-vector), apply LSTM gates.
// gpart: [4][64][4096]; c in-place per-column; h_out separate (ping-pong).
// ---------------------------------------------------------------------------
__launch_bounds__(256)
__global__ void gates_combine(const float* __restrict__ gpart,
                              const float* __restrict__ addMat,   // [64][4096] or null
                              const float* __restrict__ addRow,   // [4096] or null
                              float* __restrict__ c,
                              float* __restrict__ h_out,
                              float* __restrict__ h_store)
{
    int idx = blockIdx.x * 256 + threadIdx.x;   // 0..65535
    int m = idx >> 10, j = idx & 1023;
    float g4[4];
#pragma unroll
    for (int gate = 0; gate < 4; ++gate) {
        int n = gate * 1024 + j;
        size_t base = (size_t)m * 4096 + n;
        float v = gpart[base] + gpart[base + 64 * 4096]
                + gpart[base + 2 * 64 * 4096] + gpart[base + 3 * 64 * 4096];
        if (addMat) v += addMat[base];
        if (addRow) v += addRow[n];
        g4[gate] = v;
    }
    float cv = c[idx];
    float cn = sigmf(g4[1]) * cv + sigmf(g4[0]) * tanhf(g4[2]);
    float hn = sigmf(g4[3]) * tanhf(cn);
    c[idx] = cn;
    h_out[idx] = hn;
    if (h_store) h_store[idx] = hn;
}

// ---------------------------------------------------------------------------
// Combine 16 split-K partials for context: + b2, PReLU, + enc_pad -> xdec ctx.
// ---------------------------------------------------------------------------
__launch_bounds__(256)
__global__ void ctx_combine(const float* __restrict__ gpart2,   // [16][64][1024]
                            const float* __restrict__ b2,
                            const float* __restrict__ prelu_w,
                            const float* __restrict__ encpad,   // [64][1024]
                            float* __restrict__ xdec)           // [64][2048]
{
    int idx = blockIdx.x * 256 + threadIdx.x;   // 0..65535
    int m = idx >> 10, n = idx & 1023;
    float v = 0.f;
#pragma unroll
    for (int ks = 0; ks < 16; ++ks)
        v += gpart2[((size_t)(ks * 64 + m)) * 1024 + n];
    v += b2[n];
    float pw = prelu_w[0];
    v = (v >= 0.f) ? v : pw * v;
    v += encpad[idx];
    xdec[(size_t)m * 2048 + 1024 + n] = v;
}

// ---------------------------------------------------------------------------
// Attention: logits=[h|sample]@W1^T+b1; softmax over 80; f = sum w[s]*E[s,b,:]
// writes attA=[sample|f] and xdec[:,0:1024]=sample. One block per batch b.
// ---------------------------------------------------------------------------
__launch_bounds__(256)
__global__ void attention_step(const float* __restrict__ h,
                               const float* __restrict__ sample,
                               const float* __restrict__ W1,
                               const float* __restrict__ b1,
                               const float* __restrict__ E,
                               float* __restrict__ attA,
                               float* __restrict__ xdec)
{
    int b = blockIdx.x, tid = threadIdx.x;
    __shared__ float sm[2048];
    __shared__ float wsm[80];
    __shared__ float rbuf[128];

    for (int i = tid; i < 1024; i += 256) {
        sm[i] = h[b * 1024 + i];
        sm[1024 + i] = sample[b * 1024 + i];
    }
    __syncthreads();

    int wave = tid >> 6, lane = tid & 63;
    for (int s = wave; s < 80; s += 4) {
        float p = 0.f;
        const float* wr = W1 + (size_t)s * 2048;
        for (int k = lane; k < 2048; k += 64) p = fmaf(sm[k], wr[k], p);
        for (int off = 32; off; off >>= 1) p += __shfl_down(p, off, 64);
        if (lane == 0) wsm[s] = p + b1[s];
    }
    __syncthreads();

    float v = (tid < 80) ? wsm[tid] : -3.4e38f;
    if (tid < 128) rbuf[tid] = v;
    __syncthreads();
    for (int off = 64; off >= 1; off >>= 1) {
        if (tid < off) rbuf[tid] = fmaxf(rbuf[tid], rbuf[tid + off]);
        __syncthreads();
    }
    float mx = rbuf[0];
    __syncthreads();
    float e = (tid < 80) ? __expf(wsm[tid] - mx) : 0.f;
    if (tid < 128) rbuf[tid] = e;
    __syncthreads();
    for (int off = 64; off >= 1; off >>= 1) {
        if (tid < off) rbuf[tid] += rbuf[tid + off];
        __syncthreads();
    }
    float inv = 1.f / rbuf[0];
    __syncthreads();
    if (tid < 80) wsm[tid] = e * inv;
    __syncthreads();

    for (int hh = tid; hh < 1024; hh += 256) {
        float acc = 0.f;
        for (int s = 0; s < 80; ++s)
            acc = fmaf(wsm[s], E[((size_t)s * 64 + b) * 1024 + hh], acc);
        attA[b * 2048 + 1024 + hh] = acc;
        float smp = sm[1024 + hh];
        attA[b * 2048 + hh] = smp;
        xdec[b * 2048 + hh] = smp;
    }
}

__launch_bounds__(256)
__global__ void setup_misc(const float* __restrict__ e_bih, const float* __restrict__ e_bhh,
                           const float* __restrict__ d_bih, const float* __restrict__ d_bhh,
                           float* __restrict__ benc, float* __restrict__ bdec,
                           float* __restrict__ h_enc0, float* __restrict__ c_enc,
                           float* __restrict__ h_dec0, float* __restrict__ c_dec)
{
    int idx = blockIdx.x * 256 + threadIdx.x;   // 0..65535
    if (idx < 4096) {
        benc[idx] = e_bih[idx] + e_bhh[idx];
        bdec[idx] = d_bih[idx] + d_bhh[idx];
    }
    h_enc0[idx] = 0.f; c_enc[idx] = 0.f;
    h_dec0[idx] = 0.f; c_dec[idx] = 0.f;
}

__launch_bounds__(256)
__global__ void sample0_fill(const float* __restrict__ emW, const float* __restrict__ emb,
                             float* __restrict__ samples)
{
    int idx = blockIdx.x * 256 + threadIdx.x; // 65536
    int d = idx & 1023;
    samples[idx] = emW[(size_t)d * 20000 + 19998] + emb[d];
}

// ---------------------------------------------------------------------------
extern "C" void kernel_launch(void* const* d_in, const int* in_sizes, int n_in,
                              void* d_out, int out_size, void* d_ws, size_t ws_size,
                              hipStream_t stream)
{
    (void)in_sizes; (void)n_in; (void)out_size; (void)ws_size;

    const float* input_data     = (const float*)d_in[0];
    const float* correct_answer = (const float*)d_in[1];
    const float* enc_W_ih = (const float*)d_in[2];
    const float* enc_W_hh = (const float*)d_in[3];
    const float* enc_b_ih = (const float*)d_in[4];
    const float* enc_b_hh = (const float*)d_in[5];
    const float* dec_W_ih = (const float*)d_in[6];
    const float* dec_W_hh = (const float*)d_in[7];
    const float* dec_b_ih = (const float*)d_in[8];
    const float* dec_b_hh = (const float*)d_in[9];
    const float* in_emb_W = (const float*)d_in[10];
    const float* in_emb_b = (const float*)d_in[11];
    const float* out_emb_W = (const float*)d_in[12];
    const float* out_emb_b = (const float*)d_in[13];
    const float* att_W1 = (const float*)d_in[14];
    const float* att_b1 = (const float*)d_in[15];
    const float* att_W2 = (const float*)d_in[16];
    const float* att_b2 = (const float*)d_in[17];
    const float* prelu_w = (const float*)d_in[18];

    float* out = (float*)d_out;
    char* ws = (char*)d_ws;

    // d_out (102.4M floats) doubles as scratch until the final vocab GEMM:
    //   Xbig   = out[0 .. 20971520)           input-projection buffer [80][64][4096]
    //   gpart  = out[20971520 .. +1048576)    split-K partials  [4][64][4096]
    //   gpart2 = out[22020096 .. +1048576)    ctx partials      [16][64][1024]
    float* Xbig   = out;
    float* gpart  = out + 20971520;
    float* gpart2 = out + 22020096;

    size_t off = 0;
    auto alloc = [&](size_t nfloats) { float* p = (float*)(ws + off); off += nfloats * 4; return p; };
    float* enc_seq     = alloc(80 * 64 * 1024);
    float* enc_pad_seq = alloc(80 * 64 * 1024);
    float* samples     = alloc(80 * 64 * 1024);
    float* h_all       = alloc(80 * 64 * 1024);
    float* h_enc[2] = { alloc(64 * 1024), alloc(64 * 1024) };
    float* h_dec[2] = { alloc(64 * 1024), alloc(64 * 1024) };
    float* c_enc = alloc(64 * 1024);
    float* c_dec = alloc(64 * 1024);
    float* attA  = alloc(64 * 2048);
    float* xdec  = alloc(64 * 2048);
    float* benc_sum = alloc(4096);
    float* bdec_sum = alloc(4096);

    auto big = [&](const float* A, int lda, const float* W, int ldw,
                   float* C, int ldc, const float* bias, int M, int N, int K) {
        dim3 g((N + 127) / 128, (M + 127) / 128);
        hipLaunchKernelGGL(gemm_big, g, dim3(256), 0, stream,
                           A, lda, W, ldw, C, ldc, bias, M, N, K);
    };
    // single-source recurrent GEMM: [64,1024] @ W[4096,1024]^T, KSPLIT=4
    auto stepg1 = [&](const float* A, const float* W) {
        hipLaunchKernelGGL(step_gemm, dim3(64, 4), dim3(256), 0, stream,
                           A, 1024, 1024, W, 1024, A, 1024, W, 1024, gpart, 4096, 256);
    };
    auto gatesc = [&](const float* addMat, const float* addRow,
                      float* c, float* h_out, float* h_store) {
        hipLaunchKernelGGL(gates_combine, dim3(256), dim3(256), 0, stream,
                           gpart, addMat, addRow, c, h_out, h_store);
    };

    // setup
    hipLaunchKernelGGL(setup_misc, dim3(256), dim3(256), 0, stream,
                       enc_b_ih, enc_b_hh, dec_b_ih, dec_b_hh,
                       benc_sum, bdec_sum, h_enc[0], c_enc, h_dec[0], c_dec);

    // encoder input projection
    big(input_data, 4096, enc_W_ih, 4096, Xbig, 4096, benc_sum, 5120, 4096, 4096);

    // encoder recurrence (bias baked into Xbig)
    for (int t = 0; t < 80; ++t) {
        stepg1(h_enc[t & 1], enc_W_hh);
        gatesc(Xbig + (size_t)t * 64 * 4096, nullptr,
               c_enc, h_enc[(t + 1) & 1], enc_seq + (size_t)t * 64 * 1024);
    }
    // encoder over zero padding (x-projection = bias vector only)
    for (int t = 80; t < 160; ++t) {
        stepg1(h_enc[t & 1], enc_W_hh);
        gatesc(nullptr, benc_sum,
               c_enc, h_enc[(t + 1) & 1], enc_pad_seq + (size_t)(t - 80) * 64 * 1024);
    }

    // decoder warm-up projection (dec_in0 = [enc_seq | 0] -> first 1024 cols of dec_W_ih)
    big(enc_seq, 1024, dec_W_ih, 2048, Xbig, 4096, bdec_sum, 5120, 4096, 1024);
    for (int t = 0; t < 80; ++t) {
        stepg1(h_dec[t & 1], dec_W_hh);
        gatesc(Xbig + (size_t)t * 64 * 4096, nullptr,
               c_dec, h_dec[(t + 1) & 1], nullptr);
    }

    // teacher-forced samples
    hipLaunchKernelGGL(sample0_fill, dim3(256), dim3(256), 0, stream, in_emb_W, in_emb_b, samples);
    big(correct_answer + (size_t)64 * 20000, 20000, in_emb_W, 20000,
        samples + (size_t)64 * 1024, 1024, in_emb_b, 5056, 1024, 20000);

    // attention decode loop
    for (int t = 0; t < 80; ++t) {
        const float* sample_t = samples + (size_t)t * 64 * 1024;
        const float* encpad_t = enc_pad_seq + (size_t)t * 64 * 1024;
        float* hcur = h_dec[t & 1];
        float* hnxt = h_dec[(t + 1) & 1];

        hipLaunchKernelGGL(attention_step, dim3(64), dim3(256), 0, stream,
                           hcur, sample_t, att_W1, att_b1, enc_seq, attA, xdec);
        // context partials: attA[64,2048] @ att_W2[1024,2048]^T, KSPLIT=16
        hipLaunchKernelGGL(step_gemm, dim3(16, 16), dim3(256), 0, stream,
                           attA, 2048, 2048, att_W2, 2048, attA, 2048, att_W2, 2048,
                           gpart2, 1024, 128);
        hipLaunchKernelGGL(ctx_combine, dim3(256), dim3(256), 0, stream,
                           gpart2, att_b2, prelu_w, encpad_t, xdec);
        // g partials: [xdec(K=2048) | h(K=1024)] vs [dec_W_ih | dec_W_hh], KSPLIT=4
        hipLaunchKernelGGL(step_gemm, dim3(64, 4), dim3(256), 0, stream,
                           xdec, 2048, 2048, dec_W_ih, 2048, hcur, 1024, dec_W_hh, 1024,
                           gpart, 4096, 768);
        gatesc(nullptr, bdec_sum, c_dec, hnxt, h_all + (size_t)t * 64 * 1024);
    }

    // final vocab projection (overwrites all of d_out including scratch regions)
    big(h_all, 1024, out_emb_W, 1024, out, 20000, out_emb_b, 5120, 20000, 1024);
}

// Round 3
// 33553.351 us; speedup vs baseline: 2.7995x; 1.2018x over previous
//
#include <hip/hip_runtime.h>
#include <cstddef>
#include <cstdint>

typedef __attribute__((ext_vector_type(8))) short short8v;
typedef __attribute__((ext_vector_type(4))) float f32x4;

__device__ __forceinline__ float sigmf(float x) { return 1.0f / (1.0f + __expf(-x)); }

__device__ __forceinline__ unsigned short bf16_rn(float x) {
    union { float f; unsigned u; } v; v.f = x;
    unsigned r = v.u + 0x7FFF + ((v.u >> 16) & 1);
    return (unsigned short)(r >> 16);
}
__device__ __forceinline__ float bf16_to_f(unsigned short h) {
    union { unsigned u; float f; } v; v.u = ((unsigned)h) << 16; return v.f;
}
__device__ __forceinline__ unsigned long long pack4(unsigned short a, unsigned short b,
                                                    unsigned short c, unsigned short d) {
    return (unsigned long long)a | ((unsigned long long)b << 16)
         | ((unsigned long long)c << 32) | ((unsigned long long)d << 48);
}

// ---------------------------------------------------------------------------
// fp32 GEMM via bf16-split MFMA:  C[M,N] = A[M,K] @ W[N,K]^T + bias.
// NS=3: x = hi+mid+lo, 6 cross-pair MFMAs -> fp32-accurate (for recurrence paths).
// NS=1: hi only (plain bf16) -> output-facing GEMM (vocab).
// Tile 128x128, 4 waves (2x2 of 64x64), BK=32 (one 16x16x32 MFMA per frag/pair).
// K must be a multiple of 32. M,N guarded (loads clamped, stores guarded).
// ---------------------------------------------------------------------------
template <int NS>
__launch_bounds__(256, 2)
__global__ void gemm_mfma_split(const float* __restrict__ A, int lda,
                                const float* __restrict__ W, int ldw,
                                float* __restrict__ C, int ldc,
                                const float* __restrict__ bias,
                                int M, int N, int K)
{
    __shared__ unsigned short Abf[NS][128][40];   // pad 40 to break bank conflicts
    __shared__ unsigned short Bbf[NS][128][40];
    const int tid = threadIdx.x;
    const int m0 = blockIdx.y * 128, n0 = blockIdx.x * 128;
    const int wave = tid >> 6, lane = tid & 63;
    const int wr = wave >> 1, wc = wave & 1;
    const int lr = lane & 15, lk = (lane >> 4) * 8;

    f32x4 acc[4][4];
#pragma unroll
    for (int i = 0; i < 4; ++i)
#pragma unroll
        for (int j = 0; j < 4; ++j) acc[i][j] = (f32x4){0.f, 0.f, 0.f, 0.f};

    const int arow = tid >> 1;          // 0..127
    const int akh  = (tid & 1) * 16;    // 0 or 16

    int gr = m0 + arow; if (gr > M - 1) gr = M - 1;
    int gn = n0 + arow; if (gn > N - 1) gn = N - 1;
    const float* aptr = A + (size_t)gr * lda + akh;
    const float* wptr = W + (size_t)gn * ldw + akh;

    for (int k0 = 0; k0 < K; k0 += 32) {
#pragma unroll
        for (int q = 0; q < 4; ++q) {
            float4 v = *(const float4*)(aptr + k0 + q * 4);
            float xs[4] = {v.x, v.y, v.z, v.w};
            unsigned short h[4], hm[4], hl[4];
#pragma unroll
            for (int e = 0; e < 4; ++e) {
                h[e] = bf16_rn(xs[e]);
                if (NS == 3) {
                    float r1 = xs[e] - bf16_to_f(h[e]);
                    hm[e] = bf16_rn(r1);
                    hl[e] = bf16_rn(r1 - bf16_to_f(hm[e]));
                }
            }
            *(unsigned long long*)&Abf[0][arow][akh + q * 4] = pack4(h[0], h[1], h[2], h[3]);
            if (NS == 3) {
                *(unsigned long long*)&Abf[1][arow][akh + q * 4] = pack4(hm[0], hm[1], hm[2], hm[3]);
                *(unsigned long long*)&Abf[2][arow][akh + q * 4] = pack4(hl[0], hl[1], hl[2], hl[3]);
            }
        }
#pragma unroll
        for (int q = 0; q < 4; ++q) {
            float4 v = *(const float4*)(wptr + k0 + q * 4);
            float xs[4] = {v.x, v.y, v.z, v.w};
            unsigned short h[4], hm[4], hl[4];
#pragma unroll
            for (int e = 0; e < 4; ++e) {
                h[e] = bf16_rn(xs[e]);
                if (NS == 3) {
                    float r1 = xs[e] - bf16_to_f(h[e]);
                    hm[e] = bf16_rn(r1);
                    hl[e] = bf16_rn(r1 - bf16_to_f(hm[e]));
                }
            }
            *(unsigned long long*)&Bbf[0][arow][akh + q * 4] = pack4(h[0], h[1], h[2], h[3]);
            if (NS == 3) {
                *(unsigned long long*)&Bbf[1][arow][akh + q * 4] = pack4(hm[0], hm[1], hm[2], hm[3]);
                *(unsigned long long*)&Bbf[2][arow][akh + q * 4] = pack4(hl[0], hl[1], hl[2], hl[3]);
            }
        }
        __syncthreads();

        short8v a[NS][4], b[4];
#pragma unroll
        for (int p = 0; p < NS; ++p)
#pragma unroll
            for (int i = 0; i < 4; ++i)
                a[p][i] = *(const short8v*)&Abf[p][wr * 64 + i * 16 + lr][lk];

#pragma unroll
        for (int q = 0; q < NS; ++q) {
#pragma unroll
            for (int j = 0; j < 4; ++j)
                b[j] = *(const short8v*)&Bbf[q][wc * 64 + j * 16 + lr][lk];
            const int pmax = (NS == 1) ? 1 : (3 - q);  // pairs: (p,q) with p+q<=2
#pragma unroll
            for (int p = 0; p < 3; ++p) {
                if (p >= pmax) break;
#pragma unroll
                for (int i = 0; i < 4; ++i)
#pragma unroll
                    for (int j = 0; j < 4; ++j)
                        acc[i][j] = __builtin_amdgcn_mfma_f32_16x16x32_bf16(
                            a[p][i], b[j], acc[i][j], 0, 0, 0);
            }
        }
        __syncthreads();
    }

    const int crow = (lane >> 4) * 4;
#pragma unroll
    for (int i = 0; i < 4; ++i) {
        int mbase = m0 + wr * 64 + i * 16 + crow;
#pragma unroll
        for (int j = 0; j < 4; ++j) {
            int n = n0 + wc * 64 + j * 16 + lr;
            if (n < N) {
                float bv = bias[n];
#pragma unroll
                for (int r = 0; r < 4; ++r) {
                    int m = mbase + r;
                    if (m < M) C[(size_t)m * ldc + n] = acc[i][j][r] + bv;
                }
            }
        }
    }
}

// ---------------------------------------------------------------------------
// Split-K skinny GEMM for recurrent steps (fp32): gpart[ks][64][N] partial of
// [A1|A2][64,K1+K2] @ [W1|W2][N,K1+K2]^T over K-chunk ks. KC mult of 32.
// ---------------------------------------------------------------------------
__launch_bounds__(256)
__global__ void step_gemm(const float* __restrict__ A1, int lda1, int K1,
                          const float* __restrict__ W1, int ldw1,
                          const float* __restrict__ A2, int lda2,
                          const float* __restrict__ W2, int ldw2,
                          float* __restrict__ gpart, int N, int KC)
{
    __shared__ float Ast[32][68];
    __shared__ float Wst[32][68];
    const int tid = threadIdx.x;
    const int n0 = blockIdx.x * 64;
    const int ks = blockIdx.y;
    const int kbase = ks * KC;
    const int tm = tid >> 4, tn = tid & 15;

    float acc[4][4];
#pragma unroll
    for (int i = 0; i < 4; ++i)
#pragma unroll
        for (int j = 0; j < 4; ++j) acc[i][j] = 0.f;

    for (int kt = 0; kt < KC; kt += 32) {
        const int k0 = kbase + kt;
#pragma unroll
        for (int it = 0; it < 2; ++it) {
            int li = tid + it * 256;
            int m = li >> 3, k4 = li & 7;
            int kg = k0 + k4 * 4;
            float4 v = (kg < K1)
                ? *(const float4*)(A1 + (size_t)m * lda1 + kg)
                : *(const float4*)(A2 + (size_t)m * lda2 + (kg - K1));
            Ast[k4 * 4 + 0][m] = v.x; Ast[k4 * 4 + 1][m] = v.y;
            Ast[k4 * 4 + 2][m] = v.z; Ast[k4 * 4 + 3][m] = v.w;
        }
#pragma unroll
        for (int it = 0; it < 2; ++it) {
            int li = tid + it * 256;
            int r = li >> 3, k4 = li & 7;
            int kg = k0 + k4 * 4;
            int n = n0 + r;
            float4 v = (kg < K1)
                ? *(const float4*)(W1 + (size_t)n * ldw1 + kg)
                : *(const float4*)(W2 + (size_t)n * ldw2 + (kg - K1));
            Wst[k4 * 4 + 0][r] = v.x; Wst[k4 * 4 + 1][r] = v.y;
            Wst[k4 * 4 + 2][r] = v.z; Wst[k4 * 4 + 3][r] = v.w;
        }
        __syncthreads();
#pragma unroll
        for (int kk = 0; kk < 32; ++kk) {
            float4 a4 = *(const float4*)&Ast[kk][tm * 4];
            float4 b4 = *(const float4*)&Wst[kk][tn * 4];
            float a[4] = {a4.x, a4.y, a4.z, a4.w};
            float b[4] = {b4.x, b4.y, b4.z, b4.w};
#pragma unroll
            for (int i = 0; i < 4; ++i)
#pragma unroll
                for (int j = 0; j < 4; ++j) acc[i][j] = fmaf(a[i], b[j], acc[i][j]);
        }
        __syncthreads();
    }

#pragma unroll
    for (int i = 0; i < 4; ++i) {
        int m = tm * 4 + i;
        float4 v = make_float4(acc[i][0], acc[i][1], acc[i][2], acc[i][3]);
        *(float4*)(gpart + ((size_t)(ks * 64 + m)) * N + n0 + tn * 4) = v;
    }
}

// ---------------------------------------------------------------------------
// Combine NP split-K partials (+Xbig or +bias-vector), apply LSTM gates.
// ---------------------------------------------------------------------------
template <int NP>
__launch_bounds__(256)
__global__ void gates_combine(const float* __restrict__ gpart,
                              const float* __restrict__ addMat,
                              const float* __restrict__ addRow,
                              float* __restrict__ c,
                              float* __restrict__ h_out,
                              float* __restrict__ h_store)
{
    int idx = blockIdx.x * 256 + threadIdx.x;   // 0..65535
    int m = idx >> 10, j = idx & 1023;
    float g4[4];
#pragma unroll
    for (int gate = 0; gate < 4; ++gate) {
        int n = gate * 1024 + j;
        size_t base = (size_t)m * 4096 + n;
        float v = 0.f;
#pragma unroll
        for (int ks = 0; ks < NP; ++ks) v += gpart[base + (size_t)ks * 64 * 4096];
        if (addMat) v += addMat[base];
        if (addRow) v += addRow[n];
        g4[gate] = v;
    }
    float cv = c[idx];
    float cn = sigmf(g4[1]) * cv + sigmf(g4[0]) * tanhf(g4[2]);
    float hn = sigmf(g4[3]) * tanhf(cn);
    c[idx] = cn;
    h_out[idx] = hn;
    if (h_store) h_store[idx] = hn;
}

__launch_bounds__(256)
__global__ void ctx_combine(const float* __restrict__ gpart2,   // [16][64][1024]
                            const float* __restrict__ b2,
                            const float* __restrict__ prelu_w,
                            const float* __restrict__ encpad,
                            float* __restrict__ xdec)
{
    int idx = blockIdx.x * 256 + threadIdx.x;
    int m = idx >> 10, n = idx & 1023;
    float v = 0.f;
#pragma unroll
    for (int ks = 0; ks < 16; ++ks)
        v += gpart2[((size_t)(ks * 64 + m)) * 1024 + n];
    v += b2[n];
    float pw = prelu_w[0];
    v = (v >= 0.f) ? v : pw * v;
    v += encpad[idx];
    xdec[(size_t)m * 2048 + 1024 + n] = v;
}

__launch_bounds__(256)
__global__ void attention_step(const float* __restrict__ h,
                               const float* __restrict__ sample,
                               const float* __restrict__ W1,
                               const float* __restrict__ b1,
                               const float* __restrict__ E,
                               float* __restrict__ attA,
                               float* __restrict__ xdec)
{
    int b = blockIdx.x, tid = threadIdx.x;
    __shared__ float sm[2048];
    __shared__ float wsm[80];
    __shared__ float rbuf[128];

    for (int i = tid; i < 1024; i += 256) {
        sm[i] = h[b * 1024 + i];
        sm[1024 + i] = sample[b * 1024 + i];
    }
    __syncthreads();

    int wave = tid >> 6, lane = tid & 63;
    for (int s = wave; s < 80; s += 4) {
        float p = 0.f;
        const float* wr = W1 + (size_t)s * 2048;
        for (int k = lane; k < 2048; k += 64) p = fmaf(sm[k], wr[k], p);
        for (int off = 32; off; off >>= 1) p += __shfl_down(p, off, 64);
        if (lane == 0) wsm[s] = p + b1[s];
    }
    __syncthreads();

    float v = (tid < 80) ? wsm[tid] : -3.4e38f;
    if (tid < 128) rbuf[tid] = v;
    __syncthreads();
    for (int off = 64; off >= 1; off >>= 1) {
        if (tid < off) rbuf[tid] = fmaxf(rbuf[tid], rbuf[tid + off]);
        __syncthreads();
    }
    float mx = rbuf[0];
    __syncthreads();
    float e = (tid < 80) ? __expf(wsm[tid] - mx) : 0.f;
    if (tid < 128) rbuf[tid] = e;
    __syncthreads();
    for (int off = 64; off >= 1; off >>= 1) {
        if (tid < off) rbuf[tid] += rbuf[tid + off];
        __syncthreads();
    }
    float inv = 1.f / rbuf[0];
    __syncthreads();
    if (tid < 80) wsm[tid] = e * inv;
    __syncthreads();

    for (int hh = tid; hh < 1024; hh += 256) {
        float acc = 0.f;
        for (int s = 0; s < 80; ++s)
            acc = fmaf(wsm[s], E[((size_t)s * 64 + b) * 1024 + hh], acc);
        attA[b * 2048 + 1024 + hh] = acc;
        float smp = sm[1024 + hh];
        attA[b * 2048 + hh] = smp;
        xdec[b * 2048 + hh] = smp;
    }
}

__launch_bounds__(256)
__global__ void setup_misc(const float* __restrict__ e_bih, const float* __restrict__ e_bhh,
                           const float* __restrict__ d_bih, const float* __restrict__ d_bhh,
                           float* __restrict__ benc, float* __restrict__ bdec,
                           float* __restrict__ h_enc0, float* __restrict__ c_enc,
                           float* __restrict__ h_dec0, float* __restrict__ c_dec)
{
    int idx = blockIdx.x * 256 + threadIdx.x;
    if (idx < 4096) {
        benc[idx] = e_bih[idx] + e_bhh[idx];
        bdec[idx] = d_bih[idx] + d_bhh[idx];
    }
    h_enc0[idx] = 0.f; c_enc[idx] = 0.f;
    h_dec0[idx] = 0.f; c_dec[idx] = 0.f;
}

__launch_bounds__(256)
__global__ void sample0_fill(const float* __restrict__ emW, const float* __restrict__ emb,
                             float* __restrict__ samples)
{
    int idx = blockIdx.x * 256 + threadIdx.x; // 65536
    int d = idx & 1023;
    samples[idx] = emW[(size_t)d * 20000 + 19998] + emb[d];
}

// ---------------------------------------------------------------------------
extern "C" void kernel_launch(void* const* d_in, const int* in_sizes, int n_in,
                              void* d_out, int out_size, void* d_ws, size_t ws_size,
                              hipStream_t stream)
{
    (void)in_sizes; (void)n_in; (void)out_size; (void)ws_size;

    const float* input_data     = (const float*)d_in[0];
    const float* correct_answer = (const float*)d_in[1];
    const float* enc_W_ih = (const float*)d_in[2];
    const float* enc_W_hh = (const float*)d_in[3];
    const float* enc_b_ih = (const float*)d_in[4];
    const float* enc_b_hh = (const float*)d_in[5];
    const float* dec_W_ih = (const float*)d_in[6];
    const float* dec_W_hh = (const float*)d_in[7];
    const float* dec_b_ih = (const float*)d_in[8];
    const float* dec_b_hh = (const float*)d_in[9];
    const float* in_emb_W = (const float*)d_in[10];
    const float* in_emb_b = (const float*)d_in[11];
    const float* out_emb_W = (const float*)d_in[12];
    const float* out_emb_b = (const float*)d_in[13];
    const float* att_W1 = (const float*)d_in[14];
    const float* att_b1 = (const float*)d_in[15];
    const float* att_W2 = (const float*)d_in[16];
    const float* att_b2 = (const float*)d_in[17];
    const float* prelu_w = (const float*)d_in[18];

    float* out = (float*)d_out;
    char* ws = (char*)d_ws;

    // d_out scratch (102.4M floats) until final vocab GEMM:
    float* Xbig   = out;                 // [80][64][4096]  = 20.97M floats
    float* gpart  = out + 20971520;      // [8][64][4096]   =  2.10M
    float* gpart2 = out + 23068672;      // [16][64][1024]  =  1.05M

    size_t off = 0;
    auto alloc = [&](size_t nfloats) { float* p = (float*)(ws + off); off += nfloats * 4; return p; };
    float* enc_seq     = alloc(80 * 64 * 1024);
    float* enc_pad_seq = alloc(80 * 64 * 1024);
    float* samples     = alloc(80 * 64 * 1024);
    float* h_all       = alloc(80 * 64 * 1024);
    float* h_enc[2] = { alloc(64 * 1024), alloc(64 * 1024) };
    float* h_dec[2] = { alloc(64 * 1024), alloc(64 * 1024) };
    float* c_enc = alloc(64 * 1024);
    float* c_dec = alloc(64 * 1024);
    float* attA  = alloc(64 * 2048);
    float* xdec  = alloc(64 * 2048);
    float* benc_sum = alloc(4096);
    float* bdec_sum = alloc(4096);

    // big GEMMs via split-MFMA. NS=3 for recurrence-feeding, NS=1 for vocab.
    auto big3 = [&](const float* A, int lda, const float* W, int ldw,
                    float* C, int ldc, const float* bias, int M, int N, int K) {
        dim3 g((N + 127) / 128, (M + 127) / 128);
        hipLaunchKernelGGL((gemm_mfma_split<3>), g, dim3(256), 0, stream,
                           A, lda, W, ldw, C, ldc, bias, M, N, K);
    };
    auto big1 = [&](const float* A, int lda, const float* W, int ldw,
                    float* C, int ldc, const float* bias, int M, int N, int K) {
        dim3 g((N + 127) / 128, (M + 127) / 128);
        hipLaunchKernelGGL((gemm_mfma_split<1>), g, dim3(256), 0, stream,
                           A, lda, W, ldw, C, ldc, bias, M, N, K);
    };
    // recurrent step GEMM: [64,1024] @ W[4096,1024]^T, KSPLIT=8
    auto stepg1 = [&](const float* A, const float* W) {
        hipLaunchKernelGGL(step_gemm, dim3(64, 8), dim3(256), 0, stream,
                           A, 1024, 1024, W, 1024, A, 1024, W, 1024, gpart, 4096, 128);
    };
    auto gatesc = [&](const float* addMat, const float* addRow,
                      float* c, float* h_out, float* h_store) {
        hipLaunchKernelGGL((gates_combine<8>), dim3(256), dim3(256), 0, stream,
                           gpart, addMat, addRow, c, h_out, h_store);
    };

    hipLaunchKernelGGL(setup_misc, dim3(256), dim3(256), 0, stream,
                       enc_b_ih, enc_b_hh, dec_b_ih, dec_b_hh,
                       benc_sum, bdec_sum, h_enc[0], c_enc, h_dec[0], c_dec);

    // encoder input projection (feeds recurrence -> NS=3)
    big3(input_data, 4096, enc_W_ih, 4096, Xbig, 4096, benc_sum, 5120, 4096, 4096);

    // encoder recurrence
    for (int t = 0; t < 80; ++t) {
        stepg1(h_enc[t & 1], enc_W_hh);
        gatesc(Xbig + (size_t)t * 64 * 4096, nullptr,
               c_enc, h_enc[(t + 1) & 1], enc_seq + (size_t)t * 64 * 1024);
    }
    // encoder over zero padding
    for (int t = 80; t < 160; ++t) {
        stepg1(h_enc[t & 1], enc_W_hh);
        gatesc(nullptr, benc_sum,
               c_enc, h_enc[(t + 1) & 1], enc_pad_seq + (size_t)(t - 80) * 64 * 1024);
    }

    // decoder warm-up projection (first 1024 cols of dec_W_ih) -> NS=3
    big3(enc_seq, 1024, dec_W_ih, 2048, Xbig, 4096, bdec_sum, 5120, 4096, 1024);
    for (int t = 0; t < 80; ++t) {
        stepg1(h_dec[t & 1], dec_W_hh);
        gatesc(Xbig + (size_t)t * 64 * 4096, nullptr,
               c_dec, h_dec[(t + 1) & 1], nullptr);
    }

    // teacher-forced samples (feed decode recurrence -> NS=3)
    hipLaunchKernelGGL(sample0_fill, dim3(256), dim3(256), 0, stream, in_emb_W, in_emb_b, samples);
    big3(correct_answer + (size_t)64 * 20000, 20000, in_emb_W, 20000,
         samples + (size_t)64 * 1024, 1024, in_emb_b, 5056, 1024, 20000);

    // attention decode loop
    for (int t = 0; t < 80; ++t) {
        const float* sample_t = samples + (size_t)t * 64 * 1024;
        const float* encpad_t = enc_pad_seq + (size_t)t * 64 * 1024;
        float* hcur = h_dec[t & 1];
        float* hnxt = h_dec[(t + 1) & 1];

        hipLaunchKernelGGL(attention_step, dim3(64), dim3(256), 0, stream,
                           hcur, sample_t, att_W1, att_b1, enc_seq, attA, xdec);
        hipLaunchKernelGGL(step_gemm, dim3(16, 16), dim3(256), 0, stream,
                           attA, 2048, 2048, att_W2, 2048, attA, 2048, att_W2, 2048,
                           gpart2, 1024, 128);
        hipLaunchKernelGGL(ctx_combine, dim3(256), dim3(256), 0, stream,
                           gpart2, att_b2, prelu_w, encpad_t, xdec);
        hipLaunchKernelGGL(step_gemm, dim3(64, 8), dim3(256), 0, stream,
                           xdec, 2048, 2048, dec_W_ih, 2048, hcur, 1024, dec_W_hh, 1024,
                           gpart, 4096, 384);
        gatesc(nullptr, bdec_sum, c_dec, hnxt, h_all + (size_t)t * 64 * 1024);
    }

    // final vocab projection (output-facing -> NS=1 plain bf16 MFMA)
    big1(h_all, 1024, out_emb_W, 1024, out, 20000, out_emb_b, 5120, 20000, 1024);
}